// Round 5
// baseline (275.725 us; speedup 1.0000x reference)
//
#include <hip/hip_runtime.h>
#include <hip/hip_bf16.h>
#include <cstdint>
#include <cstddef>

// ---------------------------------------------------------------------------
// MAT_31997506355868 round 5.
// convert -> qkv_gemm (BK=64, XOR-swizzled async staging, Q pre-scaled 1/32)
// -> vt_kernel (V^T frag-major) -> attn_kernel (FLASH: unnormalized PV +
// per-lane denom, rescale at end, writes rvW; no shuffles in j-loop)
// -> colsum_kernel (column-parallel att colsum using rvW; no atomics).
// Head h = flat slab: per-head Q/K/V = (1024 x 64) row-major at h*65536.
// relu-softmax: exp args in [0,2], denom >= 1024 -> no max subtraction.
// ---------------------------------------------------------------------------

typedef short short8 __attribute__((ext_vector_type(8)));
typedef short short4v __attribute__((ext_vector_type(4)));
typedef float f32x4 __attribute__((ext_vector_type(4)));

#define MFMA32(a, b, c) __builtin_amdgcn_mfma_f32_16x16x32_bf16(a, b, c, 0, 0, 0)
#define MFMA16x16(a, b, c) __builtin_amdgcn_mfma_f32_16x16x16bf16_1k(a, b, c, 0, 0, 0)
#define ATT_SCALE 0.03125f

__device__ __forceinline__ short f2bf(float f) {
  union { float f; uint32_t u; } x; x.f = f;
  uint32_t u = x.u + 0x7fffu + ((x.u >> 16) & 1u);  // RNE
  return (short)(u >> 16);
}

// pack two fp32 -> two bf16 (truncate) in one v_perm_b32
__device__ __forceinline__ uint32_t pk_bf16_trunc(float lo, float hi) {
  return __builtin_amdgcn_perm(__float_as_uint(hi), __float_as_uint(lo),
                               0x07060302u);
}

// async global->LDS, 16B per lane; LDS dest = wave-uniform base + lane*16
#define GLDS16(gp, lp)                                                        \
  __builtin_amdgcn_global_load_lds(                                           \
      (const __attribute__((address_space(1))) void*)(gp),                    \
      (__attribute__((address_space(3))) void*)(lp), 16, 0, 0)

// ---- fp32 -> bf16 convert -------------------------------------------------
__global__ __launch_bounds__(256) void convert_kernel(
    const float* __restrict__ x, const float* __restrict__ wq,
    const float* __restrict__ wk, const float* __restrict__ wv,
    short* __restrict__ xb, short* __restrict__ wb) {
  const long XN = 4L * 1024 * 1024, WN = 1024L * 1024;
  long e = (long)(blockIdx.x * blockDim.x + threadIdx.x) * 4;
  const float* src; short* dst;
  if (e < XN)               { src = x  + e;                dst = xb + e; }
  else if (e < XN + WN)     { src = wq + (e - XN);         dst = wb + (e - XN); }
  else if (e < XN + 2 * WN) { src = wk + (e - XN - WN);    dst = wb + (e - XN); }
  else                      { src = wv + (e - XN - 2*WN);  dst = wb + (e - XN); }
  f32x4 v = *(const f32x4*)src;
  short4v o;
  o[0] = f2bf(v[0]); o[1] = f2bf(v[1]); o[2] = f2bf(v[2]); o[3] = f2bf(v[3]);
  *(short4v*)dst = o;
}

// ---- QKV projection: BK=64, XOR-swizzled staging --------------------------
// LDS layout: S[row][cg_lds*8..] holds global colgroup cg_g = cg_lds^(row&7)
// (swizzle applied to the global SOURCE address; global_load_lds dest is
// fixed lane order).  Frag read col-group = (kk*4+quad)^(lm&7) -> each quad
// spreads over all 32 banks (optimal for ds_read_b128 at 128B row stride).
__global__ __launch_bounds__(256, 3) void qkv_gemm(
    const short* __restrict__ xb, const short* __restrict__ wb,
    const float* __restrict__ bq, const float* __restrict__ bk,
    const float* __restrict__ bv, short* __restrict__ qb,
    short* __restrict__ kb, short* __restrict__ vb) {
  __shared__ short As[128 * 64];
  __shared__ short Bs[128 * 64];
  const int tid = threadIdx.x;
  const int lane = tid & 63;
  const int lm = lane & 15, quad = lane >> 4;
  const int wave = tid >> 6, wy = wave >> 1, wx = wave & 1;
  const int m0 = blockIdx.y * 128, n0 = blockIdx.x * 128;
  const int z = blockIdx.z;
  const short* w = wb + (size_t)z * (1024 * 1024);
  const float* bias = (z == 0) ? bq : (z == 1) ? bk : bv;
  short* out = (z == 0) ? qb : (z == 1) ? kb : vb;
  const float scl = (z == 0) ? ATT_SCALE : 1.0f;

  // staging pointers for chunks c = tid + 256*it (row=c>>3, cg swizzled)
  const short* gA[4]; const short* gB[4];
  short* lA[4]; short* lB[4];
#pragma unroll
  for (int it = 0; it < 4; it++) {
    const int c = it * 256 + tid;
    const int row = c >> 3, cg = (c & 7) ^ (row & 7);
    gA[it] = xb + (size_t)(m0 + row) * 1024 + cg * 8;
    gB[it] = w  + (size_t)(n0 + row) * 1024 + cg * 8;
    lA[it] = As + c * 8;
    lB[it] = Bs + c * 8;
  }

  f32x4 acc[4][4];
#pragma unroll
  for (int i = 0; i < 4; i++)
#pragma unroll
    for (int j = 0; j < 4; j++) acc[i][j] = (f32x4){0.f, 0.f, 0.f, 0.f};

  const int sw = lm & 7;  // frag-read swizzle key
  for (int k0 = 0; k0 < 1024; k0 += 64) {
#pragma unroll
    for (int it = 0; it < 4; it++) GLDS16(gA[it] + k0, lA[it]);
#pragma unroll
    for (int it = 0; it < 4; it++) GLDS16(gB[it] + k0, lB[it]);
    __syncthreads();
#pragma unroll
    for (int kk = 0; kk < 2; kk++) {
      short8 a[4], b[4];
#pragma unroll
      for (int t = 0; t < 4; t++)
        a[t] = *(const short8*)(As + (wy * 64 + t * 16 + lm) * 64 +
                                ((kk * 4 + quad) ^ sw) * 8);
#pragma unroll
      for (int t = 0; t < 4; t++)
        b[t] = *(const short8*)(Bs + (wx * 64 + t * 16 + lm) * 64 +
                                ((kk * 4 + quad) ^ sw) * 8);
#pragma unroll
      for (int mt = 0; mt < 4; mt++)
#pragma unroll
        for (int nt = 0; nt < 4; nt++)
          acc[mt][nt] = MFMA32(a[mt], b[nt], acc[mt][nt]);
    }
    __syncthreads();
  }
  // epilogue: C/D layout col=lane&15, row=quad*4+reg
#pragma unroll
  for (int nt = 0; nt < 4; nt++) {
    const int n = n0 + wx * 64 + nt * 16 + lm;
    const float bn = bias[n];
#pragma unroll
    for (int mt = 0; mt < 4; mt++) {
      const int mb = m0 + wy * 64 + mt * 16 + quad * 4;
#pragma unroll
      for (int r = 0; r < 4; r++)
        out[(size_t)(mb + r) * 1024 + n] = f2bf((acc[mt][nt][r] + bn) * scl);
    }
  }
}

// ---- V transpose into frag-major layout -----------------------------------
// vtp per head: dt-plane stride 16384, j-group (16 j) stride 256, lane*4.
__global__ __launch_bounds__(256) void vt_kernel(
    const short* __restrict__ vb, short* __restrict__ vtp) {
  __shared__ short T[64 * 72];
  const int tid = threadIdx.x;
  const int h = blockIdx.x >> 4, jb = blockIdx.x & 15;  // j-range 64
  const short* Vh = vb + (size_t)h * 65536;
  short* Vo = vtp + (size_t)h * 65536;
#pragma unroll
  for (int it = 0; it < 2; it++) {
    const int idx = it * 256 + tid;
    const int jj = idx >> 3, dg = idx & 7;
    short8 vv = *(const short8*)(Vh + (size_t)(jb * 64 + jj) * 64 + dg * 8);
    *(short8*)&T[jj * 72 + dg * 8] = vv;
  }
  __syncthreads();
#pragma unroll
  for (int it = 0; it < 4; it++) {
    const int c = it * 256 + tid;          // 1024 chunks of 4 shorts
    const int dt = c >> 8, rem = c & 255;
    const int gl = rem >> 6, qlm = rem & 63;
    const int q = qlm >> 4, lmv = qlm & 15;
    const int d = dt * 16 + lmv;
    short4v o;
#pragma unroll
    for (int u = 0; u < 4; u++) o[u] = T[(gl * 16 + q * 4 + u) * 72 + d];
    *(short4v*)(Vo + dt * 16384 + (size_t)(jb * 4 + gl) * 256 + qlm * 4) = o;
  }
}

// ---- FLASH attention: unnormalized PV + inline denom + LN -----------------
// grid 1024 = 64 heads x 16 blocks (64 rows); wave owns 16 rows (1 tile).
// Z^T = MFMA(A=K,B=Q): lane holds P^T[j=quad*4+r][i=lm] = B-operand layout
// of mfma16x16x16 -> PV directly.  denom: per-lane partials, ONE end
// reduction.  Rescale acc by rv at the end; write rvW for colsum pass.
__global__ __launch_bounds__(256, 4) void attn_kernel(
    const short* __restrict__ qb, const short* __restrict__ kb,
    const short* __restrict__ vtp, const float* __restrict__ x,
    const float* __restrict__ gamma, const float* __restrict__ beta,
    float* __restrict__ out1, float* __restrict__ rvW) {
  const int tid = threadIdx.x;
  const int lane = tid & 63, wave = tid >> 6;
  const int lm = lane & 15, quad = lane >> 4;
  const int h = blockIdx.x >> 4, bb = blockIdx.x & 15;
  const short* Qh = qb + (size_t)h * 65536;
  const short* Kh = kb + (size_t)h * 65536;
  const short* Vp = vtp + (size_t)h * 65536;
  const int i0 = bb * 64 + wave * 16;

  const short8 qA0 = *(const short8*)(Qh + (size_t)(i0 + lm) * 64 + quad * 8);
  const short8 qA1 = *(const short8*)(Qh + (size_t)(i0 + lm) * 64 + 32 + quad * 8);

  f32x4 acc[4];
#pragma unroll
  for (int t = 0; t < 4; t++) acc[t] = (f32x4){0.f, 0.f, 0.f, 0.f};
  float ds[4] = {0.f, 0.f, 0.f, 0.f};

#pragma unroll 4
  for (int j0 = 0; j0 < 1024; j0 += 16) {
    const short* kr = Kh + (size_t)(j0 + lm) * 64 + quad * 8;
    const short8 kf0 = *(const short8*)kr;
    const short8 kf1 = *(const short8*)(kr + 32);
    f32x4 z = {0.f, 0.f, 0.f, 0.f};
    z = MFMA32(kf0, qA0, z);
    z = MFMA32(kf1, qA1, z);
    float p[4];
#pragma unroll
    for (int r = 0; r < 4; r++) {
      p[r] = __expf(fmaxf(z[r], 0.f));   // unnormalized
      ds[r] += p[r];
    }
    union { uint32_t u[2]; short4v s; } pu;
    pu.u[0] = pk_bf16_trunc(p[0], p[1]);
    pu.u[1] = pk_bf16_trunc(p[2], p[3]);
    const short* vbase = Vp + (j0 >> 4) * 256 + lane * 4;
#pragma unroll
    for (int dt = 0; dt < 4; dt++) {
      const short4v vtf = *(const short4v*)(vbase + dt * 16384);
      acc[dt] = MFMA16x16(vtf, pu.s, acc[dt]);
    }
  }
  // denom for row i = i0+lm: sum own 4 partials, reduce across quads
  float t = (ds[0] + ds[1]) + (ds[2] + ds[3]);
  t += __shfl_xor(t, 16);
  t += __shfl_xor(t, 32);
  const float rv = 1.f / t;
  if (lane < 16) rvW[h * 1024 + i0 + lm] = rv;

  // ---- LN epilogue: wave owns output row m; n = lm*64 + dt*16 + quad*4+r --
  const int m = h * 64 + bb * 4 + wave;
  const int nb = lm * 64 + quad * 4;
  const float* xr = x + (size_t)m * 1024;
  float hv[4][4], s1 = 0.f, s2 = 0.f;
#pragma unroll
  for (int dt = 0; dt < 4; dt++) {
    f32x4 xv = *(const f32x4*)(xr + nb + dt * 16);
#pragma unroll
    for (int r = 0; r < 4; r++) {
      const float v = xv[r] + acc[dt][r] * rv;
      hv[dt][r] = v; s1 += v; s2 += v * v;
    }
  }
#pragma unroll
  for (int mk = 1; mk < 64; mk <<= 1) {
    s1 += __shfl_xor(s1, mk);
    s2 += __shfl_xor(s2, mk);
  }
  const float mu = s1 * (1.f / 1024.f);
  const float var = s2 * (1.f / 1024.f) - mu * mu;
  const float rstd = rsqrtf(var + 1e-5f);
  float* orow = out1 + (size_t)m * 1024;
#pragma unroll
  for (int dt = 0; dt < 4; dt++) {
    f32x4 gv = *(const f32x4*)(gamma + nb + dt * 16);
    f32x4 bv2 = *(const f32x4*)(beta + nb + dt * 16);
    f32x4 ov;
#pragma unroll
    for (int r = 0; r < 4; r++)
      ov[r] = (hv[dt][r] - mu) * rstd * gv[r] + bv2[r];
    *(f32x4*)(orow + nb + dt * 16) = ov;
  }
}

// ---- colsum: out2[h][j] = sum_i exp(relu(z_ij)) * rv_i --------------------
// Column-parallel: wave owns 16 columns (K-frags loop-invariant), sweeps i.
// Pure per-lane accumulation; one 16-lane reduction at the end; exclusive
// column ownership -> plain stores, no atomics, no memset.
__global__ __launch_bounds__(256, 4) void colsum_kernel(
    const short* __restrict__ qb, const short* __restrict__ kb,
    const float* __restrict__ rvW, float* __restrict__ out2) {
  const int tid = threadIdx.x;
  const int lane = tid & 63, wave = tid >> 6;
  const int lm = lane & 15, quad = lane >> 4;
  const int h = blockIdx.x >> 4, jb = blockIdx.x & 15;
  const int j0 = jb * 64 + wave * 16;
  const short* Qh = qb + (size_t)h * 65536;
  const short* Kh = kb + (size_t)h * 65536;

  const short* krr = Kh + (size_t)(j0 + lm) * 64 + quad * 8;
  const short8 kf0 = *(const short8*)krr;
  const short8 kf1 = *(const short8*)(krr + 32);

  f32x4 cs = {0.f, 0.f, 0.f, 0.f};
#pragma unroll 4
  for (int ib = 0; ib < 1024; ib += 16) {
    const short* qr = Qh + (size_t)(ib + lm) * 64 + quad * 8;
    const short8 qf0 = *(const short8*)qr;
    const short8 qf1 = *(const short8*)(qr + 32);
    f32x4 z = {0.f, 0.f, 0.f, 0.f};
    z = MFMA32(kf0, qf0, z);
    z = MFMA32(kf1, qf1, z);
    const float rvv = rvW[h * 1024 + ib + lm];  // row i = ib+lm
#pragma unroll
    for (int r = 0; r < 4; r++)
      cs[r] += __expf(fmaxf(z[r], 0.f)) * rvv;
  }
  // reduce over the 16 i-lanes within each quad
#pragma unroll
  for (int mk = 1; mk < 16; mk <<= 1)
#pragma unroll
    for (int r = 0; r < 4; r++) cs[r] += __shfl_xor(cs[r], mk);
  if (lm == 0)
    *(f32x4*)(out2 + h * 1024 + j0 + quad * 4) = cs;
}

extern "C" void kernel_launch(void* const* d_in, const int* in_sizes, int n_in,
                              void* d_out, int out_size, void* d_ws, size_t ws_size,
                              hipStream_t stream) {
  const float* x  = (const float*)d_in[0];
  const float* Wq = (const float*)d_in[1];
  const float* bq = (const float*)d_in[2];
  const float* Wk = (const float*)d_in[3];
  const float* bk = (const float*)d_in[4];
  const float* Wv = (const float*)d_in[5];
  const float* bv = (const float*)d_in[6];
  const float* gamma = (const float*)d_in[7];
  const float* beta  = (const float*)d_in[8];

  float* out1 = (float*)d_out;                       // 4*1024*1024
  float* out2 = out1 + 4L * 1024 * 1024;             // 64*1024 colsums

  short* xb = (short*)d_ws;                          // 4096x1024 bf16
  short* wb = xb + 4L * 1024 * 1024;                 // 3x 1024x1024 bf16
  short* qb = wb + 3L * 1024 * 1024;
  short* kb = qb + 4L * 1024 * 1024;
  short* vb = kb + 4L * 1024 * 1024;
  short* vtp = xb;                                   // reuse xb after qkv_gemm
  float* rvW = (float*)wb;                           // reuse wb after qkv_gemm

  convert_kernel<<<7168, 256, 0, stream>>>(x, Wq, Wk, Wv, xb, wb);
  qkv_gemm<<<dim3(8, 32, 3), 256, 0, stream>>>(xb, wb, bq, bk, bv, qb, kb, vb);
  vt_kernel<<<1024, 256, 0, stream>>>(vb, vtp);
  attn_kernel<<<1024, 256, 0, stream>>>(qb, kb, vtp, x, gamma, beta, out1, rvW);
  colsum_kernel<<<1024, 256, 0, stream>>>(qb, kb, rvW, out2);
}

// Round 6
// 224.367 us; speedup vs baseline: 1.2289x; 1.2289x over previous
//
#include <hip/hip_runtime.h>
#include <hip/hip_bf16.h>
#include <cstdint>
#include <cstddef>

// ---------------------------------------------------------------------------
// MAT_31997506355868 round 6.
// convert -> qkv_gemm (R4 form: BK=32, plain layout — BK=64+swizzle regressed)
// -> vt_kernel (V^T frag-major) -> attn_kernel (flash, 16 rows/wave,
// block-level K/V LDS staging via global_load_lds: 4096 waves = ~50% occ,
// inner loop reads LDS only) -> colsum_kernel (column-parallel, no atomics).
// Head h = flat slab: per-head Q/K/V = (1024 x 64) row-major at h*65536.
// relu-softmax: exp args in [0,2], denom >= 1024 -> no max subtraction.
// ---------------------------------------------------------------------------

typedef short short8 __attribute__((ext_vector_type(8)));
typedef short short4v __attribute__((ext_vector_type(4)));
typedef float f32x4 __attribute__((ext_vector_type(4)));

#define MFMA32(a, b, c) __builtin_amdgcn_mfma_f32_16x16x32_bf16(a, b, c, 0, 0, 0)
#define MFMA16x16(a, b, c) __builtin_amdgcn_mfma_f32_16x16x16bf16_1k(a, b, c, 0, 0, 0)
#define ATT_SCALE 0.03125f

__device__ __forceinline__ short f2bf(float f) {
  union { float f; uint32_t u; } x; x.f = f;
  uint32_t u = x.u + 0x7fffu + ((x.u >> 16) & 1u);  // RNE
  return (short)(u >> 16);
}

// pack two fp32 -> two bf16 (truncate) in one v_perm_b32
__device__ __forceinline__ uint32_t pk_bf16_trunc(float lo, float hi) {
  return __builtin_amdgcn_perm(__float_as_uint(hi), __float_as_uint(lo),
                               0x07060302u);
}

// async global->LDS, 16B per lane; LDS dest = wave-uniform base + lane*16
#define GLDS16(gp, lp)                                                        \
  __builtin_amdgcn_global_load_lds(                                           \
      (const __attribute__((address_space(1))) void*)(gp),                    \
      (__attribute__((address_space(3))) void*)(lp), 16, 0, 0)

// ---- fp32 -> bf16 convert -------------------------------------------------
__global__ __launch_bounds__(256) void convert_kernel(
    const float* __restrict__ x, const float* __restrict__ wq,
    const float* __restrict__ wk, const float* __restrict__ wv,
    short* __restrict__ xb, short* __restrict__ wb) {
  const long XN = 4L * 1024 * 1024, WN = 1024L * 1024;
  long e = (long)(blockIdx.x * blockDim.x + threadIdx.x) * 4;
  const float* src; short* dst;
  if (e < XN)               { src = x  + e;                dst = xb + e; }
  else if (e < XN + WN)     { src = wq + (e - XN);         dst = wb + (e - XN); }
  else if (e < XN + 2 * WN) { src = wk + (e - XN - WN);    dst = wb + (e - XN); }
  else                      { src = wv + (e - XN - 2*WN);  dst = wb + (e - XN); }
  f32x4 v = *(const f32x4*)src;
  short4v o;
  o[0] = f2bf(v[0]); o[1] = f2bf(v[1]); o[2] = f2bf(v[2]); o[3] = f2bf(v[3]);
  *(short4v*)dst = o;
}

// ---- QKV projection (R4/m97 structure, BK=32).  Q pre-scaled by 1/32. -----
__global__ __launch_bounds__(256, 3) void qkv_gemm(
    const short* __restrict__ xb, const short* __restrict__ wb,
    const float* __restrict__ bq, const float* __restrict__ bk,
    const float* __restrict__ bv, short* __restrict__ qb,
    short* __restrict__ kb, short* __restrict__ vb) {
  __shared__ short As[128 * 32];
  __shared__ short Bs[128 * 32];
  const int tid = threadIdx.x;
  const int lane = tid & 63;
  const int lm = lane & 15, quad = lane >> 4;
  const int wave = tid >> 6, wy = wave >> 1, wx = wave & 1;
  const int m0 = blockIdx.y * 128, n0 = blockIdx.x * 128;
  const int z = blockIdx.z;
  const short* w = wb + (size_t)z * (1024 * 1024);
  const float* bias = (z == 0) ? bq : (z == 1) ? bk : bv;
  short* out = (z == 0) ? qb : (z == 1) ? kb : vb;
  const float scl = (z == 0) ? ATT_SCALE : 1.0f;

  const short* gA0 = xb + (size_t)(m0 + (tid >> 2)) * 1024 + (tid & 3) * 8;
  const short* gA1 = gA0 + 64 * 1024;
  const short* gB0 = w  + (size_t)(n0 + (tid >> 2)) * 1024 + (tid & 3) * 8;
  const short* gB1 = gB0 + 64 * 1024;
  short* lA0 = As + tid * 8;
  short* lA1 = As + (tid + 256) * 8;
  short* lB0 = Bs + tid * 8;
  short* lB1 = Bs + (tid + 256) * 8;

  f32x4 acc[4][4];
#pragma unroll
  for (int i = 0; i < 4; i++)
#pragma unroll
    for (int j = 0; j < 4; j++) acc[i][j] = (f32x4){0.f, 0.f, 0.f, 0.f};

  for (int k0 = 0; k0 < 1024; k0 += 32) {
    GLDS16(gA0 + k0, lA0);
    GLDS16(gA1 + k0, lA1);
    GLDS16(gB0 + k0, lB0);
    GLDS16(gB1 + k0, lB1);
    __syncthreads();
    short8 a[4], b[4];
#pragma unroll
    for (int t = 0; t < 4; t++)
      a[t] = *(const short8*)(As + (wy * 64 + t * 16 + lm) * 32 + quad * 8);
#pragma unroll
    for (int t = 0; t < 4; t++)
      b[t] = *(const short8*)(Bs + (wx * 64 + t * 16 + lm) * 32 + quad * 8);
#pragma unroll
    for (int mt = 0; mt < 4; mt++)
#pragma unroll
      for (int nt = 0; nt < 4; nt++)
        acc[mt][nt] = MFMA32(a[mt], b[nt], acc[mt][nt]);
    __syncthreads();
  }
#pragma unroll
  for (int nt = 0; nt < 4; nt++) {
    const int n = n0 + wx * 64 + nt * 16 + lm;
    const float bn = bias[n];
#pragma unroll
    for (int mt = 0; mt < 4; mt++) {
      const int mb = m0 + wy * 64 + mt * 16 + quad * 4;
#pragma unroll
      for (int r = 0; r < 4; r++)
        out[(size_t)(mb + r) * 1024 + n] = f2bf((acc[mt][nt][r] + bn) * scl);
    }
  }
}

// ---- V transpose into frag-major layout -----------------------------------
// vtp per head: dt-plane stride 16384, j-group (16 j) stride 256, lane*4.
__global__ __launch_bounds__(256) void vt_kernel(
    const short* __restrict__ vb, short* __restrict__ vtp) {
  __shared__ short T[64 * 72];
  const int tid = threadIdx.x;
  const int h = blockIdx.x >> 4, jb = blockIdx.x & 15;  // j-range 64
  const short* Vh = vb + (size_t)h * 65536;
  short* Vo = vtp + (size_t)h * 65536;
#pragma unroll
  for (int it = 0; it < 2; it++) {
    const int idx = it * 256 + tid;
    const int jj = idx >> 3, dg = idx & 7;
    short8 vv = *(const short8*)(Vh + (size_t)(jb * 64 + jj) * 64 + dg * 8);
    *(short8*)&T[jj * 72 + dg * 8] = vv;
  }
  __syncthreads();
#pragma unroll
  for (int it = 0; it < 4; it++) {
    const int c = it * 256 + tid;          // 1024 chunks of 4 shorts
    const int dt = c >> 8, rem = c & 255;
    const int gl = rem >> 6, qlm = rem & 63;
    const int q = qlm >> 4, lmv = qlm & 15;
    const int d = dt * 16 + lmv;
    short4v o;
#pragma unroll
    for (int u = 0; u < 4; u++) o[u] = T[(gl * 16 + q * 4 + u) * 72 + d];
    *(short4v*)(Vo + dt * 16384 + (size_t)(jb * 4 + gl) * 256 + qlm * 4) = o;
  }
}

// ---- FLASH attention with block-level K/V LDS staging ---------------------
// grid 1024 = 64 heads x 16 blocks (64 rows); wave owns 16 rows.  Per chunk
// of 128 j: stage K rows (16 KB, XOR-swizzled col-groups) + V^T frag chunk
// (16 KB, lane order) via global_load_lds; inner 8 j-iters read LDS only.
// Z^T = MFMA(A=K,B=Q): lane holds P^T[j=quad*4+r][i=lm] = B-operand layout
// of mfma16x16x16 -> PV directly.  Unnormalized acc + per-lane denom;
// rescale at end; write rvW for the colsum pass.
__global__ __launch_bounds__(256, 4) void attn_kernel(
    const short* __restrict__ qb, const short* __restrict__ kb,
    const short* __restrict__ vtp, const float* __restrict__ x,
    const float* __restrict__ gamma, const float* __restrict__ beta,
    float* __restrict__ out1, float* __restrict__ rvW) {
  __shared__ short Ks[128 * 64];        // 16 KB: K rows, col-groups swizzled
  __shared__ short Vs[4 * 8 * 256];     // 16 KB: V^T frag-major chunk

  const int tid = threadIdx.x;
  const int lane = tid & 63, wave = tid >> 6;
  const int lm = lane & 15, quad = lane >> 4;
  const int h = blockIdx.x >> 4, bb = blockIdx.x & 15;
  const short* Qh = qb + (size_t)h * 65536;
  const short* Kh = kb + (size_t)h * 65536;
  const short* Vp = vtp + (size_t)h * 65536;
  const int i0 = bb * 64 + wave * 16;

  // Q A-frags (loop-invariant): A[m=lm][k=quad*8+u]
  const short8 qA0 = *(const short8*)(Qh + (size_t)(i0 + lm) * 64 + quad * 8);
  const short8 qA1 = *(const short8*)(Qh + (size_t)(i0 + lm) * 64 + 32 + quad * 8);

  // staging pointers.  K: chunk c=it*256+tid -> row jr=c>>3, slot c&7 holds
  // global col-group (c&7)^(jr&7).  V: c -> dt=c>>8, gg=(c&255)>>5, w8=c&31.
  const short* gK[4]; short* lK[4];
  const short* gV[4]; short* lV[4];
#pragma unroll
  for (int it = 0; it < 4; it++) {
    const int c = it * 256 + tid;
    const int jr = c >> 3, cg = (c & 7) ^ (jr & 7);
    gK[it] = Kh + (size_t)jr * 64 + cg * 8;
    lK[it] = Ks + c * 8;
    const int dt = c >> 8, gg = (c >> 5) & 7, w8 = c & 31;
    gV[it] = Vp + dt * 16384 + gg * 256 + w8 * 8;
    lV[it] = Vs + c * 8;
  }

  f32x4 acc[4];
#pragma unroll
  for (int t = 0; t < 4; t++) acc[t] = (f32x4){0.f, 0.f, 0.f, 0.f};
  float ds[4] = {0.f, 0.f, 0.f, 0.f};

  const int swz0 = (quad ^ (lm & 7)) * 8;        // slot for col-group quad
  const int swz1 = ((quad + 4) ^ (lm & 7)) * 8;  // slot for col-group 4+quad

  for (int ch = 0; ch < 8; ch++) {
    const int ko = ch * 8192;   // 128 rows * 64 shorts per chunk
    const int vo = ch * 2048;   // 8 groups * 256 shorts per chunk
#pragma unroll
    for (int it = 0; it < 4; it++) GLDS16(gK[it] + ko, lK[it]);
#pragma unroll
    for (int it = 0; it < 4; it++) GLDS16(gV[it] + vo, lV[it]);
    __syncthreads();
#pragma unroll
    for (int jj = 0; jj < 8; jj++) {
      const short* krow = Ks + (jj * 16 + lm) * 64;
      const short8 kf0 = *(const short8*)(krow + swz0);
      const short8 kf1 = *(const short8*)(krow + swz1);
      f32x4 z = {0.f, 0.f, 0.f, 0.f};
      z = MFMA32(kf0, qA0, z);
      z = MFMA32(kf1, qA1, z);
      float p[4];
#pragma unroll
      for (int r = 0; r < 4; r++) {
        p[r] = __expf(fmaxf(z[r], 0.f));   // unnormalized
        ds[r] += p[r];
      }
      union { uint32_t u[2]; short4v s; } pu;
      pu.u[0] = pk_bf16_trunc(p[0], p[1]);
      pu.u[1] = pk_bf16_trunc(p[2], p[3]);
      const short* vbase = Vs + jj * 256 + lane * 4;
#pragma unroll
      for (int dt = 0; dt < 4; dt++) {
        const short4v vtf = *(const short4v*)(vbase + dt * 2048);
        acc[dt] = MFMA16x16(vtf, pu.s, acc[dt]);
      }
    }
    __syncthreads();
  }
  // denom for row i = i0+lm: sum own 4 partials, reduce across quads
  float t = (ds[0] + ds[1]) + (ds[2] + ds[3]);
  t += __shfl_xor(t, 16);
  t += __shfl_xor(t, 32);
  const float rv = 1.f / t;
  if (lane < 16) rvW[h * 1024 + i0 + lm] = rv;

  // ---- LN epilogue: wave owns output row m; n = lm*64 + dt*16 + quad*4+r --
  const int m = h * 64 + bb * 4 + wave;
  const int nb = lm * 64 + quad * 4;
  const float* xr = x + (size_t)m * 1024;
  float hv[4][4], s1 = 0.f, s2 = 0.f;
#pragma unroll
  for (int dt = 0; dt < 4; dt++) {
    f32x4 xv = *(const f32x4*)(xr + nb + dt * 16);
#pragma unroll
    for (int r = 0; r < 4; r++) {
      const float v = xv[r] + acc[dt][r] * rv;
      hv[dt][r] = v; s1 += v; s2 += v * v;
    }
  }
#pragma unroll
  for (int mk = 1; mk < 64; mk <<= 1) {
    s1 += __shfl_xor(s1, mk);
    s2 += __shfl_xor(s2, mk);
  }
  const float mu = s1 * (1.f / 1024.f);
  const float var = s2 * (1.f / 1024.f) - mu * mu;
  const float rstd = rsqrtf(var + 1e-5f);
  float* orow = out1 + (size_t)m * 1024;
#pragma unroll
  for (int dt = 0; dt < 4; dt++) {
    f32x4 gv = *(const f32x4*)(gamma + nb + dt * 16);
    f32x4 bv2 = *(const f32x4*)(beta + nb + dt * 16);
    f32x4 ov;
#pragma unroll
    for (int r = 0; r < 4; r++)
      ov[r] = (hv[dt][r] - mu) * rstd * gv[r] + bv2[r];
    *(f32x4*)(orow + nb + dt * 16) = ov;
  }
}

// ---- colsum: out2[h][j] = sum_i exp(relu(z_ij)) * rv_i --------------------
// Column-parallel: wave owns 16 columns (K-frags loop-invariant), sweeps i.
// 4096 waves = ~50% occupancy; exclusive column ownership -> plain stores.
__global__ __launch_bounds__(256, 4) void colsum_kernel(
    const short* __restrict__ qb, const short* __restrict__ kb,
    const float* __restrict__ rvW, float* __restrict__ out2) {
  const int tid = threadIdx.x;
  const int lane = tid & 63, wave = tid >> 6;
  const int lm = lane & 15, quad = lane >> 4;
  const int h = blockIdx.x >> 4, jb = blockIdx.x & 15;
  const int j0 = jb * 64 + wave * 16;
  const short* Qh = qb + (size_t)h * 65536;
  const short* Kh = kb + (size_t)h * 65536;

  const short* krr = Kh + (size_t)(j0 + lm) * 64 + quad * 8;
  const short8 kf0 = *(const short8*)krr;
  const short8 kf1 = *(const short8*)(krr + 32);

  f32x4 cs = {0.f, 0.f, 0.f, 0.f};
#pragma unroll 4
  for (int ib = 0; ib < 1024; ib += 16) {
    const short* qr = Qh + (size_t)(ib + lm) * 64 + quad * 8;
    const short8 qf0 = *(const short8*)qr;
    const short8 qf1 = *(const short8*)(qr + 32);
    f32x4 z = {0.f, 0.f, 0.f, 0.f};
    z = MFMA32(kf0, qf0, z);
    z = MFMA32(kf1, qf1, z);
    const float rvv = rvW[h * 1024 + ib + lm];  // row i = ib+lm
#pragma unroll
    for (int r = 0; r < 4; r++)
      cs[r] += __expf(fmaxf(z[r], 0.f)) * rvv;
  }
  // reduce over the 16 i-lanes within each quad
#pragma unroll
  for (int mk = 1; mk < 16; mk <<= 1)
#pragma unroll
    for (int r = 0; r < 4; r++) cs[r] += __shfl_xor(cs[r], mk);
  if (lm == 0)
    *(f32x4*)(out2 + h * 1024 + j0 + quad * 4) = cs;
}

extern "C" void kernel_launch(void* const* d_in, const int* in_sizes, int n_in,
                              void* d_out, int out_size, void* d_ws, size_t ws_size,
                              hipStream_t stream) {
  const float* x  = (const float*)d_in[0];
  const float* Wq = (const float*)d_in[1];
  const float* bq = (const float*)d_in[2];
  const float* Wk = (const float*)d_in[3];
  const float* bk = (const float*)d_in[4];
  const float* Wv = (const float*)d_in[5];
  const float* bv = (const float*)d_in[6];
  const float* gamma = (const float*)d_in[7];
  const float* beta  = (const float*)d_in[8];

  float* out1 = (float*)d_out;                       // 4*1024*1024
  float* out2 = out1 + 4L * 1024 * 1024;             // 64*1024 colsums

  short* xb = (short*)d_ws;                          // 4096x1024 bf16
  short* wb = xb + 4L * 1024 * 1024;                 // 3x 1024x1024 bf16
  short* qb = wb + 3L * 1024 * 1024;
  short* kb = qb + 4L * 1024 * 1024;
  short* vb = kb + 4L * 1024 * 1024;
  short* vtp = xb;                                   // reuse xb after qkv_gemm
  float* rvW = (float*)wb;                           // reuse wb after qkv_gemm

  convert_kernel<<<7168, 256, 0, stream>>>(x, Wq, Wk, Wv, xb, wb);
  qkv_gemm<<<dim3(8, 32, 3), 256, 0, stream>>>(xb, wb, bq, bk, bv, qb, kb, vb);
  vt_kernel<<<1024, 256, 0, stream>>>(vb, vtp);
  attn_kernel<<<1024, 256, 0, stream>>>(qb, kb, vtp, x, gamma, beta, out1, rvW);
  colsum_kernel<<<1024, 256, 0, stream>>>(qb, kb, rvW, out2);
}

// Round 7
// 184.117 us; speedup vs baseline: 1.4976x; 1.2186x over previous
//
#include <hip/hip_runtime.h>
#include <hip/hip_bf16.h>
#include <cstdint>
#include <cstddef>

// ---------------------------------------------------------------------------
// MAT_31997506355868 round 7.
// convert -> qkv_gemm (BK=32 m97 form) -> vt_kernel (V^T frag-major)
// -> attn_kernel (flash, block-level K/V LDS staging)  [unchanged from R6]
// -> colsum_kernel (NEW: block-level Q+rv LDS staging, mirroring attn —
//    R6 colsum was latency-bound on redundant per-wave global Q loads).
// Head h = flat slab: per-head Q/K/V = (1024 x 64) row-major at h*65536.
// relu-softmax: exp args in [0,2], denom >= 1024 -> no max subtraction.
// ---------------------------------------------------------------------------

typedef short short8 __attribute__((ext_vector_type(8)));
typedef short short4v __attribute__((ext_vector_type(4)));
typedef float f32x4 __attribute__((ext_vector_type(4)));

#define MFMA32(a, b, c) __builtin_amdgcn_mfma_f32_16x16x32_bf16(a, b, c, 0, 0, 0)
#define MFMA16x16(a, b, c) __builtin_amdgcn_mfma_f32_16x16x16bf16_1k(a, b, c, 0, 0, 0)
#define ATT_SCALE 0.03125f

__device__ __forceinline__ short f2bf(float f) {
  union { float f; uint32_t u; } x; x.f = f;
  uint32_t u = x.u + 0x7fffu + ((x.u >> 16) & 1u);  // RNE
  return (short)(u >> 16);
}

// pack two fp32 -> two bf16 (truncate) in one v_perm_b32
__device__ __forceinline__ uint32_t pk_bf16_trunc(float lo, float hi) {
  return __builtin_amdgcn_perm(__float_as_uint(hi), __float_as_uint(lo),
                               0x07060302u);
}

// async global->LDS; LDS dest = wave-uniform base + lane*size
#define GLDS16(gp, lp)                                                        \
  __builtin_amdgcn_global_load_lds(                                           \
      (const __attribute__((address_space(1))) void*)(gp),                    \
      (__attribute__((address_space(3))) void*)(lp), 16, 0, 0)
#define GLDS4(gp, lp)                                                         \
  __builtin_amdgcn_global_load_lds(                                           \
      (const __attribute__((address_space(1))) void*)(gp),                    \
      (__attribute__((address_space(3))) void*)(lp), 4, 0, 0)

// ---- fp32 -> bf16 convert -------------------------------------------------
__global__ __launch_bounds__(256) void convert_kernel(
    const float* __restrict__ x, const float* __restrict__ wq,
    const float* __restrict__ wk, const float* __restrict__ wv,
    short* __restrict__ xb, short* __restrict__ wb) {
  const long XN = 4L * 1024 * 1024, WN = 1024L * 1024;
  long e = (long)(blockIdx.x * blockDim.x + threadIdx.x) * 4;
  const float* src; short* dst;
  if (e < XN)               { src = x  + e;                dst = xb + e; }
  else if (e < XN + WN)     { src = wq + (e - XN);         dst = wb + (e - XN); }
  else if (e < XN + 2 * WN) { src = wk + (e - XN - WN);    dst = wb + (e - XN); }
  else                      { src = wv + (e - XN - 2*WN);  dst = wb + (e - XN); }
  f32x4 v = *(const f32x4*)src;
  short4v o;
  o[0] = f2bf(v[0]); o[1] = f2bf(v[1]); o[2] = f2bf(v[2]); o[3] = f2bf(v[3]);
  *(short4v*)dst = o;
}

// ---- QKV projection (m97 structure, BK=32).  Q pre-scaled by 1/32. --------
__global__ __launch_bounds__(256, 3) void qkv_gemm(
    const short* __restrict__ xb, const short* __restrict__ wb,
    const float* __restrict__ bq, const float* __restrict__ bk,
    const float* __restrict__ bv, short* __restrict__ qb,
    short* __restrict__ kb, short* __restrict__ vb) {
  __shared__ short As[128 * 32];
  __shared__ short Bs[128 * 32];
  const int tid = threadIdx.x;
  const int lane = tid & 63;
  const int lm = lane & 15, quad = lane >> 4;
  const int wave = tid >> 6, wy = wave >> 1, wx = wave & 1;
  const int m0 = blockIdx.y * 128, n0 = blockIdx.x * 128;
  const int z = blockIdx.z;
  const short* w = wb + (size_t)z * (1024 * 1024);
  const float* bias = (z == 0) ? bq : (z == 1) ? bk : bv;
  short* out = (z == 0) ? qb : (z == 1) ? kb : vb;
  const float scl = (z == 0) ? ATT_SCALE : 1.0f;

  const short* gA0 = xb + (size_t)(m0 + (tid >> 2)) * 1024 + (tid & 3) * 8;
  const short* gA1 = gA0 + 64 * 1024;
  const short* gB0 = w  + (size_t)(n0 + (tid >> 2)) * 1024 + (tid & 3) * 8;
  const short* gB1 = gB0 + 64 * 1024;
  short* lA0 = As + tid * 8;
  short* lA1 = As + (tid + 256) * 8;
  short* lB0 = Bs + tid * 8;
  short* lB1 = Bs + (tid + 256) * 8;

  f32x4 acc[4][4];
#pragma unroll
  for (int i = 0; i < 4; i++)
#pragma unroll
    for (int j = 0; j < 4; j++) acc[i][j] = (f32x4){0.f, 0.f, 0.f, 0.f};

  for (int k0 = 0; k0 < 1024; k0 += 32) {
    GLDS16(gA0 + k0, lA0);
    GLDS16(gA1 + k0, lA1);
    GLDS16(gB0 + k0, lB0);
    GLDS16(gB1 + k0, lB1);
    __syncthreads();
    short8 a[4], b[4];
#pragma unroll
    for (int t = 0; t < 4; t++)
      a[t] = *(const short8*)(As + (wy * 64 + t * 16 + lm) * 32 + quad * 8);
#pragma unroll
    for (int t = 0; t < 4; t++)
      b[t] = *(const short8*)(Bs + (wx * 64 + t * 16 + lm) * 32 + quad * 8);
#pragma unroll
    for (int mt = 0; mt < 4; mt++)
#pragma unroll
      for (int nt = 0; nt < 4; nt++)
        acc[mt][nt] = MFMA32(a[mt], b[nt], acc[mt][nt]);
    __syncthreads();
  }
#pragma unroll
  for (int nt = 0; nt < 4; nt++) {
    const int n = n0 + wx * 64 + nt * 16 + lm;
    const float bn = bias[n];
#pragma unroll
    for (int mt = 0; mt < 4; mt++) {
      const int mb = m0 + wy * 64 + mt * 16 + quad * 4;
#pragma unroll
      for (int r = 0; r < 4; r++)
        out[(size_t)(mb + r) * 1024 + n] = f2bf((acc[mt][nt][r] + bn) * scl);
    }
  }
}

// ---- V transpose into frag-major layout -----------------------------------
// vtp per head: dt-plane stride 16384, j-group (16 j) stride 256, lane*4.
__global__ __launch_bounds__(256) void vt_kernel(
    const short* __restrict__ vb, short* __restrict__ vtp) {
  __shared__ short T[64 * 72];
  const int tid = threadIdx.x;
  const int h = blockIdx.x >> 4, jb = blockIdx.x & 15;  // j-range 64
  const short* Vh = vb + (size_t)h * 65536;
  short* Vo = vtp + (size_t)h * 65536;
#pragma unroll
  for (int it = 0; it < 2; it++) {
    const int idx = it * 256 + tid;
    const int jj = idx >> 3, dg = idx & 7;
    short8 vv = *(const short8*)(Vh + (size_t)(jb * 64 + jj) * 64 + dg * 8);
    *(short8*)&T[jj * 72 + dg * 8] = vv;
  }
  __syncthreads();
#pragma unroll
  for (int it = 0; it < 4; it++) {
    const int c = it * 256 + tid;          // 1024 chunks of 4 shorts
    const int dt = c >> 8, rem = c & 255;
    const int gl = rem >> 6, qlm = rem & 63;
    const int q = qlm >> 4, lmv = qlm & 15;
    const int d = dt * 16 + lmv;
    short4v o;
#pragma unroll
    for (int u = 0; u < 4; u++) o[u] = T[(gl * 16 + q * 4 + u) * 72 + d];
    *(short4v*)(Vo + dt * 16384 + (size_t)(jb * 4 + gl) * 256 + qlm * 4) = o;
  }
}

// ---- FLASH attention with block-level K/V LDS staging (R6) ----------------
__global__ __launch_bounds__(256, 4) void attn_kernel(
    const short* __restrict__ qb, const short* __restrict__ kb,
    const short* __restrict__ vtp, const float* __restrict__ x,
    const float* __restrict__ gamma, const float* __restrict__ beta,
    float* __restrict__ out1, float* __restrict__ rvW) {
  __shared__ short Ks[128 * 64];        // 16 KB: K rows, col-groups swizzled
  __shared__ short Vs[4 * 8 * 256];     // 16 KB: V^T frag-major chunk

  const int tid = threadIdx.x;
  const int lane = tid & 63, wave = tid >> 6;
  const int lm = lane & 15, quad = lane >> 4;
  const int h = blockIdx.x >> 4, bb = blockIdx.x & 15;
  const short* Qh = qb + (size_t)h * 65536;
  const short* Kh = kb + (size_t)h * 65536;
  const short* Vp = vtp + (size_t)h * 65536;
  const int i0 = bb * 64 + wave * 16;

  const short8 qA0 = *(const short8*)(Qh + (size_t)(i0 + lm) * 64 + quad * 8);
  const short8 qA1 = *(const short8*)(Qh + (size_t)(i0 + lm) * 64 + 32 + quad * 8);

  const short* gK[4]; short* lK[4];
  const short* gV[4]; short* lV[4];
#pragma unroll
  for (int it = 0; it < 4; it++) {
    const int c = it * 256 + tid;
    const int jr = c >> 3, cg = (c & 7) ^ (jr & 7);
    gK[it] = Kh + (size_t)jr * 64 + cg * 8;
    lK[it] = Ks + c * 8;
    const int dt = c >> 8, gg = (c >> 5) & 7, w8 = c & 31;
    gV[it] = Vp + dt * 16384 + gg * 256 + w8 * 8;
    lV[it] = Vs + c * 8;
  }

  f32x4 acc[4];
#pragma unroll
  for (int t = 0; t < 4; t++) acc[t] = (f32x4){0.f, 0.f, 0.f, 0.f};
  float ds[4] = {0.f, 0.f, 0.f, 0.f};

  const int swz0 = (quad ^ (lm & 7)) * 8;
  const int swz1 = ((quad + 4) ^ (lm & 7)) * 8;

  for (int ch = 0; ch < 8; ch++) {
    const int ko = ch * 8192;
    const int vo = ch * 2048;
#pragma unroll
    for (int it = 0; it < 4; it++) GLDS16(gK[it] + ko, lK[it]);
#pragma unroll
    for (int it = 0; it < 4; it++) GLDS16(gV[it] + vo, lV[it]);
    __syncthreads();
#pragma unroll
    for (int jj = 0; jj < 8; jj++) {
      const short* krow = Ks + (jj * 16 + lm) * 64;
      const short8 kf0 = *(const short8*)(krow + swz0);
      const short8 kf1 = *(const short8*)(krow + swz1);
      f32x4 z = {0.f, 0.f, 0.f, 0.f};
      z = MFMA32(kf0, qA0, z);
      z = MFMA32(kf1, qA1, z);
      float p[4];
#pragma unroll
      for (int r = 0; r < 4; r++) {
        p[r] = __expf(fmaxf(z[r], 0.f));   // unnormalized
        ds[r] += p[r];
      }
      union { uint32_t u[2]; short4v s; } pu;
      pu.u[0] = pk_bf16_trunc(p[0], p[1]);
      pu.u[1] = pk_bf16_trunc(p[2], p[3]);
      const short* vbase = Vs + jj * 256 + lane * 4;
#pragma unroll
      for (int dt = 0; dt < 4; dt++) {
        const short4v vtf = *(const short4v*)(vbase + dt * 2048);
        acc[dt] = MFMA16x16(vtf, pu.s, acc[dt]);
      }
    }
    __syncthreads();
  }
  float t = (ds[0] + ds[1]) + (ds[2] + ds[3]);
  t += __shfl_xor(t, 16);
  t += __shfl_xor(t, 32);
  const float rv = 1.f / t;
  if (lane < 16) rvW[h * 1024 + i0 + lm] = rv;

  // ---- LN epilogue: wave owns output row m; n = lm*64 + dt*16 + quad*4+r --
  const int m = h * 64 + bb * 4 + wave;
  const int nb = lm * 64 + quad * 4;
  const float* xr = x + (size_t)m * 1024;
  float hv[4][4], s1 = 0.f, s2 = 0.f;
#pragma unroll
  for (int dt = 0; dt < 4; dt++) {
    f32x4 xv = *(const f32x4*)(xr + nb + dt * 16);
#pragma unroll
    for (int r = 0; r < 4; r++) {
      const float v = xv[r] + acc[dt][r] * rv;
      hv[dt][r] = v; s1 += v; s2 += v * v;
    }
  }
#pragma unroll
  for (int mk = 1; mk < 64; mk <<= 1) {
    s1 += __shfl_xor(s1, mk);
    s2 += __shfl_xor(s2, mk);
  }
  const float mu = s1 * (1.f / 1024.f);
  const float var = s2 * (1.f / 1024.f) - mu * mu;
  const float rstd = rsqrtf(var + 1e-5f);
  float* orow = out1 + (size_t)m * 1024;
#pragma unroll
  for (int dt = 0; dt < 4; dt++) {
    f32x4 gv = *(const f32x4*)(gamma + nb + dt * 16);
    f32x4 bv2 = *(const f32x4*)(beta + nb + dt * 16);
    f32x4 ov;
#pragma unroll
    for (int r = 0; r < 4; r++)
      ov[r] = (hv[dt][r] - mu) * rstd * gv[r] + bv2[r];
    *(f32x4*)(orow + nb + dt * 16) = ov;
  }
}

// ---- colsum with block-level Q+rv LDS staging -----------------------------
// out2[h][j] = sum_i exp(relu(z_ij)) * rv_i.  grid 1024 = 64 heads x 16
// j-blocks (64 cols); wave owns 16 cols, K-frags loop-invariant in regs.
// Per chunk of 128 i: stage Q rows (16 KB, XOR-swizzled) via GLDS16 and the
// rv chunk (512 B) via GLDS4 from waves 0-1; inner 8 iters read LDS only.
// Exclusive column ownership -> plain stores, no atomics.
__global__ __launch_bounds__(256, 4) void colsum_kernel(
    const short* __restrict__ qb, const short* __restrict__ kb,
    const float* __restrict__ rvW, float* __restrict__ out2) {
  __shared__ short Qs[128 * 64];   // 16 KB: Q rows, col-groups swizzled
  __shared__ float rvS[128];       // 512 B: rv chunk

  const int tid = threadIdx.x;
  const int lane = tid & 63, wave = tid >> 6;
  const int lm = lane & 15, quad = lane >> 4;
  const int h = blockIdx.x >> 4, jb = blockIdx.x & 15;
  const int j0 = jb * 64 + wave * 16;
  const short* Qh = qb + (size_t)h * 65536;
  const short* Kh = kb + (size_t)h * 65536;
  const float* rvh = rvW + h * 1024;

  // K frags for own 16 columns (loop-invariant)
  const short* krr = Kh + (size_t)(j0 + lm) * 64 + quad * 8;
  const short8 kf0 = *(const short8*)krr;
  const short8 kf1 = *(const short8*)(krr + 32);

  // staging pointers: chunk c=it*256+tid -> row ir=c>>3, slot c&7 holds
  // global col-group (c&7)^(ir&7)
  const short* gQ[4]; short* lQ[4];
#pragma unroll
  for (int it = 0; it < 4; it++) {
    const int c = it * 256 + tid;
    const int ir = c >> 3, cg = (c & 7) ^ (ir & 7);
    gQ[it] = Qh + (size_t)ir * 64 + cg * 8;
    lQ[it] = Qs + c * 8;
  }

  const int swz0 = (quad ^ (lm & 7)) * 8;
  const int swz1 = ((quad + 4) ^ (lm & 7)) * 8;

  f32x4 cs = {0.f, 0.f, 0.f, 0.f};

  for (int ch = 0; ch < 8; ch++) {
    const int qo = ch * 8192;   // 128 rows * 64 shorts
#pragma unroll
    for (int it = 0; it < 4; it++) GLDS16(gQ[it] + qo, lQ[it]);
    if (wave < 2)
      GLDS4(rvh + ch * 128 + wave * 64 + lane, rvS + wave * 64);
    __syncthreads();
#pragma unroll
    for (int ii = 0; ii < 8; ii++) {
      const short* qrow = Qs + (ii * 16 + lm) * 64;
      const short8 qf0 = *(const short8*)(qrow + swz0);
      const short8 qf1 = *(const short8*)(qrow + swz1);
      f32x4 z = {0.f, 0.f, 0.f, 0.f};
      z = MFMA32(kf0, qf0, z);
      z = MFMA32(kf1, qf1, z);
      const float rvv = rvS[ii * 16 + lm];  // row i = ch*128 + ii*16 + lm
#pragma unroll
      for (int r = 0; r < 4; r++)
        cs[r] += __expf(fmaxf(z[r], 0.f)) * rvv;
    }
    __syncthreads();
  }
  // reduce over the 16 i-lanes within each quad
#pragma unroll
  for (int mk = 1; mk < 16; mk <<= 1)
#pragma unroll
    for (int r = 0; r < 4; r++) cs[r] += __shfl_xor(cs[r], mk);
  if (lm == 0)
    *(f32x4*)(out2 + h * 1024 + j0 + quad * 4) = cs;
}

extern "C" void kernel_launch(void* const* d_in, const int* in_sizes, int n_in,
                              void* d_out, int out_size, void* d_ws, size_t ws_size,
                              hipStream_t stream) {
  const float* x  = (const float*)d_in[0];
  const float* Wq = (const float*)d_in[1];
  const float* bq = (const float*)d_in[2];
  const float* Wk = (const float*)d_in[3];
  const float* bk = (const float*)d_in[4];
  const float* Wv = (const float*)d_in[5];
  const float* bv = (const float*)d_in[6];
  const float* gamma = (const float*)d_in[7];
  const float* beta  = (const float*)d_in[8];

  float* out1 = (float*)d_out;                       // 4*1024*1024
  float* out2 = out1 + 4L * 1024 * 1024;             // 64*1024 colsums

  short* xb = (short*)d_ws;                          // 4096x1024 bf16
  short* wb = xb + 4L * 1024 * 1024;                 // 3x 1024x1024 bf16
  short* qb = wb + 3L * 1024 * 1024;
  short* kb = qb + 4L * 1024 * 1024;
  short* vb = kb + 4L * 1024 * 1024;
  short* vtp = xb;                                   // reuse xb after qkv_gemm
  float* rvW = (float*)wb;                           // reuse wb after qkv_gemm

  convert_kernel<<<7168, 256, 0, stream>>>(x, Wq, Wk, Wv, xb, wb);
  qkv_gemm<<<dim3(8, 32, 3), 256, 0, stream>>>(xb, wb, bq, bk, bv, qb, kb, vb);
  vt_kernel<<<1024, 256, 0, stream>>>(vb, vtp);
  attn_kernel<<<1024, 256, 0, stream>>>(qb, kb, vtp, x, gamma, beta, out1, rvW);
  colsum_kernel<<<1024, 256, 0, stream>>>(qb, kb, rvW, out2);
}

// Round 8
// 183.507 us; speedup vs baseline: 1.5025x; 1.0033x over previous
//
#include <hip/hip_runtime.h>
#include <hip/hip_bf16.h>
#include <cstdint>
#include <cstddef>

// ---------------------------------------------------------------------------
// MAT_31997506355868 round 8.
// convert -> qkv_gemm (BK=32 m97 form; z==2 epilogue writes V^T frag-major
// directly -> vt_kernel deleted) -> attn_kernel (flash, 64-j chunks,
// ping-pong K/V LDS prefetch: one barrier/chunk, loads in flight across
// compute) -> colsum_kernel (same ping-pong staging of Q+rv).
// Head h = flat slab: per-head Q/K/V = (1024 x 64) row-major at h*65536.
// relu-softmax: exp args in [0,2], denom >= 1024 -> no max subtraction.
// ---------------------------------------------------------------------------

typedef short short8 __attribute__((ext_vector_type(8)));
typedef short short4v __attribute__((ext_vector_type(4)));
typedef float f32x4 __attribute__((ext_vector_type(4)));

#define MFMA32(a, b, c) __builtin_amdgcn_mfma_f32_16x16x32_bf16(a, b, c, 0, 0, 0)
#define MFMA16x16(a, b, c) __builtin_amdgcn_mfma_f32_16x16x16bf16_1k(a, b, c, 0, 0, 0)
#define ATT_SCALE 0.03125f

__device__ __forceinline__ short f2bf(float f) {
  union { float f; uint32_t u; } x; x.f = f;
  uint32_t u = x.u + 0x7fffu + ((x.u >> 16) & 1u);  // RNE
  return (short)(u >> 16);
}

// pack two fp32 -> two bf16 (truncate) in one v_perm_b32
__device__ __forceinline__ uint32_t pk_bf16_trunc(float lo, float hi) {
  return __builtin_amdgcn_perm(__float_as_uint(hi), __float_as_uint(lo),
                               0x07060302u);
}

// async global->LDS; LDS dest = wave-uniform base + lane*size
#define GLDS16(gp, lp)                                                        \
  __builtin_amdgcn_global_load_lds(                                           \
      (const __attribute__((address_space(1))) void*)(gp),                    \
      (__attribute__((address_space(3))) void*)(lp), 16, 0, 0)
#define GLDS4(gp, lp)                                                         \
  __builtin_amdgcn_global_load_lds(                                           \
      (const __attribute__((address_space(1))) void*)(gp),                    \
      (__attribute__((address_space(3))) void*)(lp), 4, 0, 0)

// ---- fp32 -> bf16 convert -------------------------------------------------
__global__ __launch_bounds__(256) void convert_kernel(
    const float* __restrict__ x, const float* __restrict__ wq,
    const float* __restrict__ wk, const float* __restrict__ wv,
    short* __restrict__ xb, short* __restrict__ wb) {
  const long XN = 4L * 1024 * 1024, WN = 1024L * 1024;
  long e = (long)(blockIdx.x * blockDim.x + threadIdx.x) * 4;
  const float* src; short* dst;
  if (e < XN)               { src = x  + e;                dst = xb + e; }
  else if (e < XN + WN)     { src = wq + (e - XN);         dst = wb + (e - XN); }
  else if (e < XN + 2 * WN) { src = wk + (e - XN - WN);    dst = wb + (e - XN); }
  else                      { src = wv + (e - XN - 2*WN);  dst = wb + (e - XN); }
  f32x4 v = *(const f32x4*)src;
  short4v o;
  o[0] = f2bf(v[0]); o[1] = f2bf(v[1]); o[2] = f2bf(v[2]); o[3] = f2bf(v[3]);
  *(short4v*)dst = o;
}

// ---- QKV projection (m97 structure, BK=32).  Q pre-scaled by 1/32. --------
// z==2 (V): epilogue writes V^T frag-major (vtp) directly — same store count
// as row-major, vt_kernel eliminated.  vtp index for C[m][n]:
//   h=m>>6, d=n&63, j=(m&63)*16+(n>>6)  ->
//   h*65536 + ((n>>4)&3)*16384 + (m&63)*256 + (((n>>8)&3)*16+(n&15))*4
//   + ((n>>6)&3)
__global__ __launch_bounds__(256, 3) void qkv_gemm(
    const short* __restrict__ xb, const short* __restrict__ wb,
    const float* __restrict__ bq, const float* __restrict__ bk,
    const float* __restrict__ bv, short* __restrict__ qb,
    short* __restrict__ kb, short* __restrict__ vtp) {
  __shared__ short As[128 * 32];
  __shared__ short Bs[128 * 32];
  const int tid = threadIdx.x;
  const int lane = tid & 63;
  const int lm = lane & 15, quad = lane >> 4;
  const int wave = tid >> 6, wy = wave >> 1, wx = wave & 1;
  const int m0 = blockIdx.y * 128, n0 = blockIdx.x * 128;
  const int z = blockIdx.z;
  const short* w = wb + (size_t)z * (1024 * 1024);
  const float* bias = (z == 0) ? bq : (z == 1) ? bk : bv;
  const float scl = (z == 0) ? ATT_SCALE : 1.0f;

  const short* gA0 = xb + (size_t)(m0 + (tid >> 2)) * 1024 + (tid & 3) * 8;
  const short* gA1 = gA0 + 64 * 1024;
  const short* gB0 = w  + (size_t)(n0 + (tid >> 2)) * 1024 + (tid & 3) * 8;
  const short* gB1 = gB0 + 64 * 1024;
  short* lA0 = As + tid * 8;
  short* lA1 = As + (tid + 256) * 8;
  short* lB0 = Bs + tid * 8;
  short* lB1 = Bs + (tid + 256) * 8;

  f32x4 acc[4][4];
#pragma unroll
  for (int i = 0; i < 4; i++)
#pragma unroll
    for (int j = 0; j < 4; j++) acc[i][j] = (f32x4){0.f, 0.f, 0.f, 0.f};

  for (int k0 = 0; k0 < 1024; k0 += 32) {
    GLDS16(gA0 + k0, lA0);
    GLDS16(gA1 + k0, lA1);
    GLDS16(gB0 + k0, lB0);
    GLDS16(gB1 + k0, lB1);
    __syncthreads();
    short8 a[4], b[4];
#pragma unroll
    for (int t = 0; t < 4; t++)
      a[t] = *(const short8*)(As + (wy * 64 + t * 16 + lm) * 32 + quad * 8);
#pragma unroll
    for (int t = 0; t < 4; t++)
      b[t] = *(const short8*)(Bs + (wx * 64 + t * 16 + lm) * 32 + quad * 8);
#pragma unroll
    for (int mt = 0; mt < 4; mt++)
#pragma unroll
      for (int nt = 0; nt < 4; nt++)
        acc[mt][nt] = MFMA32(a[mt], b[nt], acc[mt][nt]);
    __syncthreads();
  }
  if (z == 2) {
    // V: write transposed frag-major directly
#pragma unroll
    for (int nt = 0; nt < 4; nt++) {
      const int n = n0 + wx * 64 + nt * 16 + lm;
      const float bn = bias[n];
      const size_t nbase = (size_t)((n >> 4) & 3) * 16384 +
                           (size_t)((((n >> 8) & 3) * 16 + (n & 15)) * 4 +
                                    ((n >> 6) & 3));
#pragma unroll
      for (int mt = 0; mt < 4; mt++) {
#pragma unroll
        for (int r = 0; r < 4; r++) {
          const int m = m0 + wy * 64 + mt * 16 + quad * 4 + r;
          vtp[(size_t)(m >> 6) * 65536 + nbase + (size_t)(m & 63) * 256] =
              f2bf(acc[mt][nt][r] + bn);
        }
      }
    }
  } else {
    short* out = (z == 0) ? qb : kb;
#pragma unroll
    for (int nt = 0; nt < 4; nt++) {
      const int n = n0 + wx * 64 + nt * 16 + lm;
      const float bn = bias[n];
#pragma unroll
      for (int mt = 0; mt < 4; mt++) {
        const int mb = m0 + wy * 64 + mt * 16 + quad * 4;
#pragma unroll
        for (int r = 0; r < 4; r++)
          out[(size_t)(mb + r) * 1024 + n] = f2bf((acc[mt][nt][r] + bn) * scl);
      }
    }
  }
}

// ---- FLASH attention: 64-j chunks, ping-pong K/V prefetch -----------------
// grid 1024 = 64 heads x 16 blocks (64 rows); wave owns 16 rows.
// Per chunk: stage K (8 KB, XOR-swizzled col-groups) + V^T frag chunk (8 KB)
// into buf b^1 while computing 4 j-iters from buf b; ONE barrier per chunk,
// drains loads issued a full compute-phase earlier.
__global__ __launch_bounds__(256, 4) void attn_kernel(
    const short* __restrict__ qb, const short* __restrict__ kb,
    const short* __restrict__ vtp, const float* __restrict__ x,
    const float* __restrict__ gamma, const float* __restrict__ beta,
    float* __restrict__ out1, float* __restrict__ rvW) {
  __shared__ short Ks[2][64 * 64];      // 2 x 8 KB
  __shared__ short Vs[2][4 * 4 * 256];  // 2 x 8 KB

  const int tid = threadIdx.x;
  const int lane = tid & 63, wave = tid >> 6;
  const int lm = lane & 15, quad = lane >> 4;
  const int h = blockIdx.x >> 4, bb = blockIdx.x & 15;
  const short* Qh = qb + (size_t)h * 65536;
  const short* Kh = kb + (size_t)h * 65536;
  const short* Vp = vtp + (size_t)h * 65536;
  const int i0 = bb * 64 + wave * 16;

  const short8 qA0 = *(const short8*)(Qh + (size_t)(i0 + lm) * 64 + quad * 8);
  const short8 qA1 = *(const short8*)(Qh + (size_t)(i0 + lm) * 64 + 32 + quad * 8);

  // staging pointers (chunk-invariant parts)
  const int c0 = tid, c1 = tid + 256;
  const short* gK0 = Kh + (size_t)(c0 >> 3) * 64 + ((c0 & 7) ^ ((c0 >> 3) & 7)) * 8;
  const short* gK1 = Kh + (size_t)(c1 >> 3) * 64 + ((c1 & 7) ^ ((c1 >> 3) & 7)) * 8;
  const short* gV0 = Vp + (c0 >> 7) * 16384 + ((c0 >> 5) & 3) * 256 + (c0 & 31) * 8;
  const short* gV1 = Vp + (c1 >> 7) * 16384 + ((c1 >> 5) & 3) * 256 + (c1 & 31) * 8;
  const int lK0 = c0 * 8, lK1 = c1 * 8;

  f32x4 acc[4];
#pragma unroll
  for (int t = 0; t < 4; t++) acc[t] = (f32x4){0.f, 0.f, 0.f, 0.f};
  float ds[4] = {0.f, 0.f, 0.f, 0.f};

  const int swz0 = (quad ^ (lm & 7)) * 8;
  const int swz1 = ((quad + 4) ^ (lm & 7)) * 8;

  // stage chunk 0 into buf 0
  GLDS16(gK0, &Ks[0][0] + lK0);
  GLDS16(gK1, &Ks[0][0] + lK1);
  GLDS16(gV0, &Vs[0][0] + lK0);
  GLDS16(gV1, &Vs[0][0] + lK1);

  for (int ch = 0; ch < 16; ch++) {
    const int b = ch & 1;
    __syncthreads();              // stage(ch) complete; buf b^1 free
    if (ch < 15) {                // prefetch chunk ch+1 into buf b^1
      const int ko = (ch + 1) * 4096, vo = (ch + 1) * 1024;
      GLDS16(gK0 + ko, &Ks[b ^ 1][0] + lK0);
      GLDS16(gK1 + ko, &Ks[b ^ 1][0] + lK1);
      GLDS16(gV0 + vo, &Vs[b ^ 1][0] + lK0);
      GLDS16(gV1 + vo, &Vs[b ^ 1][0] + lK1);
    }
#pragma unroll
    for (int jj = 0; jj < 4; jj++) {
      const short* krow = &Ks[b][(jj * 16 + lm) * 64];
      const short8 kf0 = *(const short8*)(krow + swz0);
      const short8 kf1 = *(const short8*)(krow + swz1);
      f32x4 z = {0.f, 0.f, 0.f, 0.f};
      z = MFMA32(kf0, qA0, z);
      z = MFMA32(kf1, qA1, z);
      float p[4];
#pragma unroll
      for (int r = 0; r < 4; r++) {
        p[r] = __expf(fmaxf(z[r], 0.f));   // unnormalized
        ds[r] += p[r];
      }
      union { uint32_t u[2]; short4v s; } pu;
      pu.u[0] = pk_bf16_trunc(p[0], p[1]);
      pu.u[1] = pk_bf16_trunc(p[2], p[3]);
      const short* vbase = &Vs[b][jj * 256 + lane * 4];
#pragma unroll
      for (int dt = 0; dt < 4; dt++) {
        const short4v vtf = *(const short4v*)(vbase + dt * 1024);
        acc[dt] = MFMA16x16(vtf, pu.s, acc[dt]);
      }
    }
  }
  float t = (ds[0] + ds[1]) + (ds[2] + ds[3]);
  t += __shfl_xor(t, 16);
  t += __shfl_xor(t, 32);
  const float rv = 1.f / t;
  if (lane < 16) rvW[h * 1024 + i0 + lm] = rv;

  // ---- LN epilogue: wave owns output row m; n = lm*64 + dt*16 + quad*4+r --
  const int m = h * 64 + bb * 4 + wave;
  const int nb = lm * 64 + quad * 4;
  const float* xr = x + (size_t)m * 1024;
  float hv[4][4], s1 = 0.f, s2 = 0.f;
#pragma unroll
  for (int dt = 0; dt < 4; dt++) {
    f32x4 xv = *(const f32x4*)(xr + nb + dt * 16);
#pragma unroll
    for (int r = 0; r < 4; r++) {
      const float v = xv[r] + acc[dt][r] * rv;
      hv[dt][r] = v; s1 += v; s2 += v * v;
    }
  }
#pragma unroll
  for (int mk = 1; mk < 64; mk <<= 1) {
    s1 += __shfl_xor(s1, mk);
    s2 += __shfl_xor(s2, mk);
  }
  const float mu = s1 * (1.f / 1024.f);
  const float var = s2 * (1.f / 1024.f) - mu * mu;
  const float rstd = rsqrtf(var + 1e-5f);
  float* orow = out1 + (size_t)m * 1024;
#pragma unroll
  for (int dt = 0; dt < 4; dt++) {
    f32x4 gv = *(const f32x4*)(gamma + nb + dt * 16);
    f32x4 bv2 = *(const f32x4*)(beta + nb + dt * 16);
    f32x4 ov;
#pragma unroll
    for (int r = 0; r < 4; r++)
      ov[r] = (hv[dt][r] - mu) * rstd * gv[r] + bv2[r];
    *(f32x4*)(orow + nb + dt * 16) = ov;
  }
}

// ---- colsum: 64-i chunks, ping-pong Q+rv prefetch -------------------------
// out2[h][j] = sum_i exp(relu(z_ij)) * rv_i.  grid 1024 = 64 heads x 16
// j-blocks; wave owns 16 cols, K-frags loop-invariant in regs.
__global__ __launch_bounds__(256, 4) void colsum_kernel(
    const short* __restrict__ qb, const short* __restrict__ kb,
    const float* __restrict__ rvW, float* __restrict__ out2) {
  __shared__ short Qs[2][64 * 64];  // 2 x 8 KB
  __shared__ float rvS[2][64];

  const int tid = threadIdx.x;
  const int lane = tid & 63, wave = tid >> 6;
  const int lm = lane & 15, quad = lane >> 4;
  const int h = blockIdx.x >> 4, jb = blockIdx.x & 15;
  const int j0 = jb * 64 + wave * 16;
  const short* Qh = qb + (size_t)h * 65536;
  const short* Kh = kb + (size_t)h * 65536;
  const float* rvh = rvW + h * 1024;

  const short* krr = Kh + (size_t)(j0 + lm) * 64 + quad * 8;
  const short8 kf0 = *(const short8*)krr;
  const short8 kf1 = *(const short8*)(krr + 32);

  const int c0 = tid, c1 = tid + 256;
  const short* gQ0 = Qh + (size_t)(c0 >> 3) * 64 + ((c0 & 7) ^ ((c0 >> 3) & 7)) * 8;
  const short* gQ1 = Qh + (size_t)(c1 >> 3) * 64 + ((c1 & 7) ^ ((c1 >> 3) & 7)) * 8;
  const int lQ0 = c0 * 8, lQ1 = c1 * 8;

  const int swz0 = (quad ^ (lm & 7)) * 8;
  const int swz1 = ((quad + 4) ^ (lm & 7)) * 8;

  f32x4 cs = {0.f, 0.f, 0.f, 0.f};

  // stage chunk 0 into buf 0
  GLDS16(gQ0, &Qs[0][0] + lQ0);
  GLDS16(gQ1, &Qs[0][0] + lQ1);
  if (wave == 0) GLDS4(rvh + lane, &rvS[0][0]);

  for (int ch = 0; ch < 16; ch++) {
    const int b = ch & 1;
    __syncthreads();              // stage(ch) complete; buf b^1 free
    if (ch < 15) {
      const int qo = (ch + 1) * 4096;
      GLDS16(gQ0 + qo, &Qs[b ^ 1][0] + lQ0);
      GLDS16(gQ1 + qo, &Qs[b ^ 1][0] + lQ1);
      if (wave == 0) GLDS4(rvh + (ch + 1) * 64 + lane, &rvS[b ^ 1][0]);
    }
#pragma unroll
    for (int ii = 0; ii < 4; ii++) {
      const short* qrow = &Qs[b][(ii * 16 + lm) * 64];
      const short8 qf0 = *(const short8*)(qrow + swz0);
      const short8 qf1 = *(const short8*)(qrow + swz1);
      f32x4 z = {0.f, 0.f, 0.f, 0.f};
      z = MFMA32(kf0, qf0, z);
      z = MFMA32(kf1, qf1, z);
      const float rvv = rvS[b][ii * 16 + lm];
#pragma unroll
      for (int r = 0; r < 4; r++)
        cs[r] += __expf(fmaxf(z[r], 0.f)) * rvv;
    }
  }
  // reduce over the 16 i-lanes within each quad
#pragma unroll
  for (int mk = 1; mk < 16; mk <<= 1)
#pragma unroll
    for (int r = 0; r < 4; r++) cs[r] += __shfl_xor(cs[r], mk);
  if (lm == 0)
    *(f32x4*)(out2 + h * 1024 + j0 + quad * 4) = cs;
}

extern "C" void kernel_launch(void* const* d_in, const int* in_sizes, int n_in,
                              void* d_out, int out_size, void* d_ws, size_t ws_size,
                              hipStream_t stream) {
  const float* x  = (const float*)d_in[0];
  const float* Wq = (const float*)d_in[1];
  const float* bq = (const float*)d_in[2];
  const float* Wk = (const float*)d_in[3];
  const float* bk = (const float*)d_in[4];
  const float* Wv = (const float*)d_in[5];
  const float* bv = (const float*)d_in[6];
  const float* gamma = (const float*)d_in[7];
  const float* beta  = (const float*)d_in[8];

  float* out1 = (float*)d_out;                       // 4*1024*1024
  float* out2 = out1 + 4L * 1024 * 1024;             // 64*1024 colsums

  short* xb = (short*)d_ws;                          // 4096x1024 bf16
  short* wb = xb + 4L * 1024 * 1024;                 // 3x 1024x1024 bf16
  short* qb = wb + 3L * 1024 * 1024;
  short* kb = qb + 4L * 1024 * 1024;
  short* vtp = kb + 4L * 1024 * 1024;                // V^T frag-major
  float* rvW = (float*)wb;                           // reuse wb after qkv_gemm

  convert_kernel<<<7168, 256, 0, stream>>>(x, Wq, Wk, Wv, xb, wb);
  qkv_gemm<<<dim3(8, 32, 3), 256, 0, stream>>>(xb, wb, bq, bk, bv, qb, kb, vtp);
  attn_kernel<<<1024, 256, 0, stream>>>(qb, kb, vtp, x, gamma, beta, out1, rvW);
  colsum_kernel<<<1024, 256, 0, stream>>>(qb, kb, rvW, out2);
}

// Round 9
// 182.704 us; speedup vs baseline: 1.5091x; 1.0044x over previous
//
#include <hip/hip_runtime.h>
#include <hip/hip_bf16.h>
#include <cstdint>
#include <cstddef>

// ---------------------------------------------------------------------------
// MAT_31997506355868 round 9.
// convert -> qkv_gemm (BK=32 m97 form; z==2 writes V^T frag-major directly)
// -> attn_kernel (flash, 2 i-tiles/wave + ping-pong K/V LDS staging: LDS
// reads amortized over 32 rows, 2 MFMA chains/wave) -> colsum_kernel
// (2 j-tiles/wave + ping-pong Q staging).
// Head h = flat slab: per-head Q/K/V = (1024 x 64) row-major at h*65536.
// relu-softmax: exp args in [0,2], denom >= 1024 -> no max subtraction.
// ---------------------------------------------------------------------------

typedef short short8 __attribute__((ext_vector_type(8)));
typedef short short4v __attribute__((ext_vector_type(4)));
typedef float f32x4 __attribute__((ext_vector_type(4)));

#define MFMA32(a, b, c) __builtin_amdgcn_mfma_f32_16x16x32_bf16(a, b, c, 0, 0, 0)
#define MFMA16x16(a, b, c) __builtin_amdgcn_mfma_f32_16x16x16bf16_1k(a, b, c, 0, 0, 0)
#define ATT_SCALE 0.03125f

__device__ __forceinline__ short f2bf(float f) {
  union { float f; uint32_t u; } x; x.f = f;
  uint32_t u = x.u + 0x7fffu + ((x.u >> 16) & 1u);  // RNE
  return (short)(u >> 16);
}

// pack two fp32 -> two bf16 (truncate) in one v_perm_b32
__device__ __forceinline__ uint32_t pk_bf16_trunc(float lo, float hi) {
  return __builtin_amdgcn_perm(__float_as_uint(hi), __float_as_uint(lo),
                               0x07060302u);
}

// async global->LDS; LDS dest = wave-uniform base + lane*size
#define GLDS16(gp, lp)                                                        \
  __builtin_amdgcn_global_load_lds(                                           \
      (const __attribute__((address_space(1))) void*)(gp),                    \
      (__attribute__((address_space(3))) void*)(lp), 16, 0, 0)
#define GLDS4(gp, lp)                                                         \
  __builtin_amdgcn_global_load_lds(                                           \
      (const __attribute__((address_space(1))) void*)(gp),                    \
      (__attribute__((address_space(3))) void*)(lp), 4, 0, 0)

// ---- fp32 -> bf16 convert -------------------------------------------------
__global__ __launch_bounds__(256) void convert_kernel(
    const float* __restrict__ x, const float* __restrict__ wq,
    const float* __restrict__ wk, const float* __restrict__ wv,
    short* __restrict__ xb, short* __restrict__ wb) {
  const long XN = 4L * 1024 * 1024, WN = 1024L * 1024;
  long e = (long)(blockIdx.x * blockDim.x + threadIdx.x) * 4;
  const float* src; short* dst;
  if (e < XN)               { src = x  + e;                dst = xb + e; }
  else if (e < XN + WN)     { src = wq + (e - XN);         dst = wb + (e - XN); }
  else if (e < XN + 2 * WN) { src = wk + (e - XN - WN);    dst = wb + (e - XN); }
  else                      { src = wv + (e - XN - 2*WN);  dst = wb + (e - XN); }
  f32x4 v = *(const f32x4*)src;
  short4v o;
  o[0] = f2bf(v[0]); o[1] = f2bf(v[1]); o[2] = f2bf(v[2]); o[3] = f2bf(v[3]);
  *(short4v*)dst = o;
}

// ---- QKV projection (m97 structure, BK=32).  Q pre-scaled by 1/32. --------
// z==2 (V): epilogue writes V^T frag-major (vtp) directly.
__global__ __launch_bounds__(256, 3) void qkv_gemm(
    const short* __restrict__ xb, const short* __restrict__ wb,
    const float* __restrict__ bq, const float* __restrict__ bk,
    const float* __restrict__ bv, short* __restrict__ qb,
    short* __restrict__ kb, short* __restrict__ vtp) {
  __shared__ short As[128 * 32];
  __shared__ short Bs[128 * 32];
  const int tid = threadIdx.x;
  const int lane = tid & 63;
  const int lm = lane & 15, quad = lane >> 4;
  const int wave = tid >> 6, wy = wave >> 1, wx = wave & 1;
  const int m0 = blockIdx.y * 128, n0 = blockIdx.x * 128;
  const int z = blockIdx.z;
  const short* w = wb + (size_t)z * (1024 * 1024);
  const float* bias = (z == 0) ? bq : (z == 1) ? bk : bv;
  const float scl = (z == 0) ? ATT_SCALE : 1.0f;

  const short* gA0 = xb + (size_t)(m0 + (tid >> 2)) * 1024 + (tid & 3) * 8;
  const short* gA1 = gA0 + 64 * 1024;
  const short* gB0 = w  + (size_t)(n0 + (tid >> 2)) * 1024 + (tid & 3) * 8;
  const short* gB1 = gB0 + 64 * 1024;
  short* lA0 = As + tid * 8;
  short* lA1 = As + (tid + 256) * 8;
  short* lB0 = Bs + tid * 8;
  short* lB1 = Bs + (tid + 256) * 8;

  f32x4 acc[4][4];
#pragma unroll
  for (int i = 0; i < 4; i++)
#pragma unroll
    for (int j = 0; j < 4; j++) acc[i][j] = (f32x4){0.f, 0.f, 0.f, 0.f};

  for (int k0 = 0; k0 < 1024; k0 += 32) {
    GLDS16(gA0 + k0, lA0);
    GLDS16(gA1 + k0, lA1);
    GLDS16(gB0 + k0, lB0);
    GLDS16(gB1 + k0, lB1);
    __syncthreads();
    short8 a[4], b[4];
#pragma unroll
    for (int t = 0; t < 4; t++)
      a[t] = *(const short8*)(As + (wy * 64 + t * 16 + lm) * 32 + quad * 8);
#pragma unroll
    for (int t = 0; t < 4; t++)
      b[t] = *(const short8*)(Bs + (wx * 64 + t * 16 + lm) * 32 + quad * 8);
#pragma unroll
    for (int mt = 0; mt < 4; mt++)
#pragma unroll
      for (int nt = 0; nt < 4; nt++)
        acc[mt][nt] = MFMA32(a[mt], b[nt], acc[mt][nt]);
    __syncthreads();
  }
  if (z == 2) {
    // V: write transposed frag-major directly
#pragma unroll
    for (int nt = 0; nt < 4; nt++) {
      const int n = n0 + wx * 64 + nt * 16 + lm;
      const float bn = bias[n];
      const size_t nbase = (size_t)((n >> 4) & 3) * 16384 +
                           (size_t)((((n >> 8) & 3) * 16 + (n & 15)) * 4 +
                                    ((n >> 6) & 3));
#pragma unroll
      for (int mt = 0; mt < 4; mt++) {
#pragma unroll
        for (int r = 0; r < 4; r++) {
          const int m = m0 + wy * 64 + mt * 16 + quad * 4 + r;
          vtp[(size_t)(m >> 6) * 65536 + nbase + (size_t)(m & 63) * 256] =
              f2bf(acc[mt][nt][r] + bn);
        }
      }
    }
  } else {
    short* out = (z == 0) ? qb : kb;
#pragma unroll
    for (int nt = 0; nt < 4; nt++) {
      const int n = n0 + wx * 64 + nt * 16 + lm;
      const float bn = bias[n];
#pragma unroll
      for (int mt = 0; mt < 4; mt++) {
        const int mb = m0 + wy * 64 + mt * 16 + quad * 4;
#pragma unroll
        for (int r = 0; r < 4; r++)
          out[(size_t)(mb + r) * 1024 + n] = f2bf((acc[mt][nt][r] + bn) * scl);
      }
    }
  }
}

// ---- FLASH attention: 2 i-tiles/wave, 64-j chunks, ping-pong K/V ----------
// grid 512 = 64 heads x 8 blocks (128 rows); wave owns 32 rows (tiles at i0,
// i0+16).  K/V staged once per chunk, frags shared by both tiles (2x issue
// economy vs R6).  Z^T identity: lane holds P^T[j=quad*4+r][i=lm] = B-operand
// of mfma16x16x16 -> PV directly.  Unnormalized acc + per-lane denom.
__global__ __launch_bounds__(256, 2) void attn_kernel(
    const short* __restrict__ qb, const short* __restrict__ kb,
    const short* __restrict__ vtp, const float* __restrict__ x,
    const float* __restrict__ gamma, const float* __restrict__ beta,
    float* __restrict__ out1, float* __restrict__ rvW) {
  __shared__ short Ks[2][64 * 64];      // 2 x 8 KB
  __shared__ short Vs[2][4 * 4 * 256];  // 2 x 8 KB

  const int tid = threadIdx.x;
  const int lane = tid & 63, wave = tid >> 6;
  const int lm = lane & 15, quad = lane >> 4;
  const int h = blockIdx.x >> 3, bb = blockIdx.x & 7;
  const short* Qh = qb + (size_t)h * 65536;
  const short* Kh = kb + (size_t)h * 65536;
  const short* Vp = vtp + (size_t)h * 65536;
  const int i0 = bb * 128 + wave * 32;   // tiles at i0 and i0+16

  const short8 qA0 = *(const short8*)(Qh + (size_t)(i0 + lm) * 64 + quad * 8);
  const short8 qA1 = *(const short8*)(Qh + (size_t)(i0 + lm) * 64 + 32 + quad * 8);
  const short8 qB0 = *(const short8*)(Qh + (size_t)(i0 + 16 + lm) * 64 + quad * 8);
  const short8 qB1 = *(const short8*)(Qh + (size_t)(i0 + 16 + lm) * 64 + 32 + quad * 8);

  // staging pointers (chunk-invariant parts)
  const int c0 = tid, c1 = tid + 256;
  const short* gK0 = Kh + (size_t)(c0 >> 3) * 64 + ((c0 & 7) ^ ((c0 >> 3) & 7)) * 8;
  const short* gK1 = Kh + (size_t)(c1 >> 3) * 64 + ((c1 & 7) ^ ((c1 >> 3) & 7)) * 8;
  const short* gV0 = Vp + (c0 >> 7) * 16384 + ((c0 >> 5) & 3) * 256 + (c0 & 31) * 8;
  const short* gV1 = Vp + (c1 >> 7) * 16384 + ((c1 >> 5) & 3) * 256 + (c1 & 31) * 8;
  const int lK0 = c0 * 8, lK1 = c1 * 8;

  f32x4 accA[4], accB[4];
#pragma unroll
  for (int t = 0; t < 4; t++) {
    accA[t] = (f32x4){0.f, 0.f, 0.f, 0.f};
    accB[t] = (f32x4){0.f, 0.f, 0.f, 0.f};
  }
  float dsA[4] = {0.f, 0.f, 0.f, 0.f};
  float dsB[4] = {0.f, 0.f, 0.f, 0.f};

  const int swz0 = (quad ^ (lm & 7)) * 8;
  const int swz1 = ((quad + 4) ^ (lm & 7)) * 8;

  // stage chunk 0 into buf 0
  GLDS16(gK0, &Ks[0][0] + lK0);
  GLDS16(gK1, &Ks[0][0] + lK1);
  GLDS16(gV0, &Vs[0][0] + lK0);
  GLDS16(gV1, &Vs[0][0] + lK1);

  for (int ch = 0; ch < 16; ch++) {
    const int b = ch & 1;
    __syncthreads();              // stage(ch) complete; buf b^1 free
    if (ch < 15) {                // prefetch chunk ch+1 into buf b^1
      const int ko = (ch + 1) * 4096, vo = (ch + 1) * 1024;
      GLDS16(gK0 + ko, &Ks[b ^ 1][0] + lK0);
      GLDS16(gK1 + ko, &Ks[b ^ 1][0] + lK1);
      GLDS16(gV0 + vo, &Vs[b ^ 1][0] + lK0);
      GLDS16(gV1 + vo, &Vs[b ^ 1][0] + lK1);
    }
#pragma unroll
    for (int jj = 0; jj < 4; jj++) {
      const short* krow = &Ks[b][(jj * 16 + lm) * 64];
      const short8 kf0 = *(const short8*)(krow + swz0);
      const short8 kf1 = *(const short8*)(krow + swz1);
      f32x4 zA = {0.f, 0.f, 0.f, 0.f};
      zA = MFMA32(kf0, qA0, zA);
      zA = MFMA32(kf1, qA1, zA);
      f32x4 zB = {0.f, 0.f, 0.f, 0.f};
      zB = MFMA32(kf0, qB0, zB);
      zB = MFMA32(kf1, qB1, zB);
      float pA[4], pB[4];
#pragma unroll
      for (int r = 0; r < 4; r++) {
        pA[r] = __expf(fmaxf(zA[r], 0.f));   // unnormalized
        dsA[r] += pA[r];
        pB[r] = __expf(fmaxf(zB[r], 0.f));
        dsB[r] += pB[r];
      }
      union { uint32_t u[2]; short4v s; } puA, puB;
      puA.u[0] = pk_bf16_trunc(pA[0], pA[1]);
      puA.u[1] = pk_bf16_trunc(pA[2], pA[3]);
      puB.u[0] = pk_bf16_trunc(pB[0], pB[1]);
      puB.u[1] = pk_bf16_trunc(pB[2], pB[3]);
      const short* vbase = &Vs[b][jj * 256 + lane * 4];
#pragma unroll
      for (int dt = 0; dt < 4; dt++) {
        const short4v vtf = *(const short4v*)(vbase + dt * 1024);
        accA[dt] = MFMA16x16(vtf, puA.s, accA[dt]);
        accB[dt] = MFMA16x16(vtf, puB.s, accB[dt]);
      }
    }
  }
  float tA = (dsA[0] + dsA[1]) + (dsA[2] + dsA[3]);
  tA += __shfl_xor(tA, 16);
  tA += __shfl_xor(tA, 32);
  float tB = (dsB[0] + dsB[1]) + (dsB[2] + dsB[3]);
  tB += __shfl_xor(tB, 16);
  tB += __shfl_xor(tB, 32);
  const float rvA = 1.f / tA;
  const float rvB = 1.f / tB;
  if (lane < 16) {
    rvW[h * 1024 + i0 + lm] = rvA;
    rvW[h * 1024 + i0 + 16 + lm] = rvB;
  }

  // ---- LN epilogue (R4-verified 2-tile): n = lm*64 + dt*16 + quad*4+r -----
  const int mA = h * 64 + bb * 8 + wave * 2;  // tile A row; tile B = mA+1
  const int nb = lm * 64 + quad * 4;
#pragma unroll
  for (int tile = 0; tile < 2; tile++) {
    const int m = mA + tile;
    const f32x4* accT = tile ? accB : accA;
    const float rv = tile ? rvB : rvA;
    const float* xr = x + (size_t)m * 1024;
    float hv[4][4], s1 = 0.f, s2 = 0.f;
#pragma unroll
    for (int dt = 0; dt < 4; dt++) {
      f32x4 xv = *(const f32x4*)(xr + nb + dt * 16);
#pragma unroll
      for (int r = 0; r < 4; r++) {
        const float v = xv[r] + accT[dt][r] * rv;
        hv[dt][r] = v; s1 += v; s2 += v * v;
      }
    }
#pragma unroll
    for (int mk = 1; mk < 64; mk <<= 1) {
      s1 += __shfl_xor(s1, mk);
      s2 += __shfl_xor(s2, mk);
    }
    const float mu = s1 * (1.f / 1024.f);
    const float var = s2 * (1.f / 1024.f) - mu * mu;
    const float rstd = rsqrtf(var + 1e-5f);
    float* orow = out1 + (size_t)m * 1024;
#pragma unroll
    for (int dt = 0; dt < 4; dt++) {
      f32x4 gv = *(const f32x4*)(gamma + nb + dt * 16);
      f32x4 bv2 = *(const f32x4*)(beta + nb + dt * 16);
      f32x4 ov;
#pragma unroll
      for (int r = 0; r < 4; r++)
        ov[r] = (hv[dt][r] - mu) * rstd * gv[r] + bv2[r];
      *(f32x4*)(orow + nb + dt * 16) = ov;
    }
  }
}

// ---- colsum: 2 j-tiles/wave, 64-i chunks, ping-pong Q+rv ------------------
// out2[h][j] = sum_i exp(relu(z_ij)) * rv_i.  grid 512 = 64 heads x 8
// j-blocks (128 cols); wave owns 32 cols (2 K-frag sets, loop-invariant);
// Q staging shared.  Exclusive column ownership -> plain stores.
__global__ __launch_bounds__(256, 2) void colsum_kernel(
    const short* __restrict__ qb, const short* __restrict__ kb,
    const float* __restrict__ rvW, float* __restrict__ out2) {
  __shared__ short Qs[2][64 * 64];  // 2 x 8 KB
  __shared__ float rvS[2][64];

  const int tid = threadIdx.x;
  const int lane = tid & 63, wave = tid >> 6;
  const int lm = lane & 15, quad = lane >> 4;
  const int h = blockIdx.x >> 3, jb = blockIdx.x & 7;
  const int j0 = jb * 128 + wave * 32;   // tiles at j0 and j0+16
  const short* Qh = qb + (size_t)h * 65536;
  const short* Kh = kb + (size_t)h * 65536;
  const float* rvh = rvW + h * 1024;

  const short* krA = Kh + (size_t)(j0 + lm) * 64 + quad * 8;
  const short8 kA0 = *(const short8*)krA;
  const short8 kA1 = *(const short8*)(krA + 32);
  const short* krB = Kh + (size_t)(j0 + 16 + lm) * 64 + quad * 8;
  const short8 kB0 = *(const short8*)krB;
  const short8 kB1 = *(const short8*)(krB + 32);

  const int c0 = tid, c1 = tid + 256;
  const short* gQ0 = Qh + (size_t)(c0 >> 3) * 64 + ((c0 & 7) ^ ((c0 >> 3) & 7)) * 8;
  const short* gQ1 = Qh + (size_t)(c1 >> 3) * 64 + ((c1 & 7) ^ ((c1 >> 3) & 7)) * 8;
  const int lQ0 = c0 * 8, lQ1 = c1 * 8;

  const int swz0 = (quad ^ (lm & 7)) * 8;
  const int swz1 = ((quad + 4) ^ (lm & 7)) * 8;

  f32x4 csA = {0.f, 0.f, 0.f, 0.f};
  f32x4 csB = {0.f, 0.f, 0.f, 0.f};

  // stage chunk 0 into buf 0
  GLDS16(gQ0, &Qs[0][0] + lQ0);
  GLDS16(gQ1, &Qs[0][0] + lQ1);
  if (wave == 0) GLDS4(rvh + lane, &rvS[0][0]);

  for (int ch = 0; ch < 16; ch++) {
    const int b = ch & 1;
    __syncthreads();              // stage(ch) complete; buf b^1 free
    if (ch < 15) {
      const int qo = (ch + 1) * 4096;
      GLDS16(gQ0 + qo, &Qs[b ^ 1][0] + lQ0);
      GLDS16(gQ1 + qo, &Qs[b ^ 1][0] + lQ1);
      if (wave == 0) GLDS4(rvh + (ch + 1) * 64 + lane, &rvS[b ^ 1][0]);
    }
#pragma unroll
    for (int ii = 0; ii < 4; ii++) {
      const short* qrow = &Qs[b][(ii * 16 + lm) * 64];
      const short8 qf0 = *(const short8*)(qrow + swz0);
      const short8 qf1 = *(const short8*)(qrow + swz1);
      f32x4 zA = {0.f, 0.f, 0.f, 0.f};
      zA = MFMA32(kA0, qf0, zA);
      zA = MFMA32(kA1, qf1, zA);
      f32x4 zB = {0.f, 0.f, 0.f, 0.f};
      zB = MFMA32(kB0, qf0, zB);
      zB = MFMA32(kB1, qf1, zB);
      const float rvv = rvS[b][ii * 16 + lm];
#pragma unroll
      for (int r = 0; r < 4; r++) {
        csA[r] += __expf(fmaxf(zA[r], 0.f)) * rvv;
        csB[r] += __expf(fmaxf(zB[r], 0.f)) * rvv;
      }
    }
  }
  // reduce over the 16 i-lanes within each quad
#pragma unroll
  for (int mk = 1; mk < 16; mk <<= 1)
#pragma unroll
    for (int r = 0; r < 4; r++) {
      csA[r] += __shfl_xor(csA[r], mk);
      csB[r] += __shfl_xor(csB[r], mk);
    }
  if (lm == 0) {
    *(f32x4*)(out2 + h * 1024 + j0 + quad * 4) = csA;
    *(f32x4*)(out2 + h * 1024 + j0 + 16 + quad * 4) = csB;
  }
}

extern "C" void kernel_launch(void* const* d_in, const int* in_sizes, int n_in,
                              void* d_out, int out_size, void* d_ws, size_t ws_size,
                              hipStream_t stream) {
  const float* x  = (const float*)d_in[0];
  const float* Wq = (const float*)d_in[1];
  const float* bq = (const float*)d_in[2];
  const float* Wk = (const float*)d_in[3];
  const float* bk = (const float*)d_in[4];
  const float* Wv = (const float*)d_in[5];
  const float* bv = (const float*)d_in[6];
  const float* gamma = (const float*)d_in[7];
  const float* beta  = (const float*)d_in[8];

  float* out1 = (float*)d_out;                       // 4*1024*1024
  float* out2 = out1 + 4L * 1024 * 1024;             // 64*1024 colsums

  short* xb = (short*)d_ws;                          // 4096x1024 bf16
  short* wb = xb + 4L * 1024 * 1024;                 // 3x 1024x1024 bf16
  short* qb = wb + 3L * 1024 * 1024;
  short* kb = qb + 4L * 1024 * 1024;
  short* vtp = kb + 4L * 1024 * 1024;                // V^T frag-major
  float* rvW = (float*)wb;                           // reuse wb after qkv_gemm

  convert_kernel<<<7168, 256, 0, stream>>>(x, Wq, Wk, Wv, xb, wb);
  qkv_gemm<<<dim3(8, 32, 3), 256, 0, stream>>>(xb, wb, bq, bk, bv, qb, kb, vtp);
  attn_kernel<<<512, 256, 0, stream>>>(qb, kb, vtp, x, gamma, beta, out1, rvW);
  colsum_kernel<<<512, 256, 0, stream>>>(qb, kb, rvW, out2);
}